// Round 11
// baseline (684.293 us; speedup 1.0000x reference)
//
#include <hip/hip_runtime.h>
#include <hip/hip_bf16.h>

#define T_SEQ 1024
#define CHUNK 64
#define NCHUNK 16
#define NBLK 257   // cooperative grid: block 0 = chain, 1..256 = batch (1024 rows each)

__device__ __forceinline__ float fast_sigmoid(float x) {
    return 1.0f / (1.0f + __expf(-x));
}
__device__ __forceinline__ float fast_tanh(float x) {
    float e = __expf(2.0f * x);
    return 1.0f - 2.0f / (e + 1.0f);
}

// K1: precompute u-dependent parts of both RNN linears (+bias)
__global__ __launch_bounds__(256) void k_rnn_pre(
    const float* __restrict__ u,
    const float* __restrict__ i2h_w, const float* __restrict__ i2h_b,
    const float* __restrict__ h2o_w, const float* __restrict__ h2o_b,
    float* __restrict__ pre_i, float* __restrict__ pre_o) {
    int idx = blockIdx.x * 256 + threadIdx.x;   // 0..65535
    int k = idx >> 6, i = idx & 63;
    float a = i2h_b[i], b = h2o_b[i];
#pragma unroll
    for (int c = 0; c < 8; ++c) {
        float uv = u[k * 8 + c];
        a += uv * i2h_w[i * 72 + c];
        b += uv * h2o_w[i * 72 + c];
    }
    pre_i[idx] = a;
    pre_o[idx] = b;
}

// ---- packed weight block layout (floats), produced by k_repack ----
#define L_XW1 0
#define L_UW1 1360
#define L_XW2 2720
#define L_UW2 3120
#define L_XW3 3520
#define L_UW3 4800
#define L_CWT 6080
#define L_XB1 14272
#define L_XB2 14292
#define L_UB1 14312
#define L_UB2 14332
#define L_XB3 14352
#define L_UB3 14416
#define L_CB  14480
#define L_TOT 14544   // 58176 bytes

__global__ __launch_bounds__(256) void k_repack(
    const float* __restrict__ xw1, const float* __restrict__ uw1,
    const float* __restrict__ xw2, const float* __restrict__ uw2,
    const float* __restrict__ xw3, const float* __restrict__ uw3,
    const float* __restrict__ cw,
    const float* __restrict__ xb1, const float* __restrict__ xb2,
    const float* __restrict__ ub1, const float* __restrict__ ub2,
    const float* __restrict__ xb3, const float* __restrict__ ub3,
    const float* __restrict__ cb, float* __restrict__ wp) {
    int i = blockIdx.x * 256 + threadIdx.x;
    if (i >= L_TOT) return;
    float v = 0.0f;
    if (i < 1360) {
        int o = i / 68, c = i - o * 68;
        if (c == 0) v = xw1[o * 65];
        else if (c >= 4) v = xw1[o * 65 + c - 3];
    } else if (i < 2720) {
        int j = i - 1360; int o = j / 68, c = j - o * 68;
        if (c == 0) v = uw1[o * 65];
        else if (c >= 4) v = uw1[o * 65 + c - 3];
    } else if (i < 3120) v = xw2[i - 2720];
    else if (i < 3520) v = uw2[i - 3120];
    else if (i < 4800) v = xw3[i - 3520];
    else if (i < 6080) v = uw3[i - 4800];
    else if (i < 14272) {
        int j = i - 6080; int row = j >> 6, s = j & 63;
        v = cw[s * 128 + row];
    }
    else if (i < 14292) v = xb1[i - 14272];
    else if (i < 14312) v = xb2[i - 14292];
    else if (i < 14332) v = ub1[i - 14312];
    else if (i < 14352) v = ub2[i - 14332];
    else if (i < 14416) v = xb3[i - 14352];
    else if (i < 14480) v = ub3[i - 14416];
    else v = cb[i - 14480];
    wp[i] = v;
}

// ---- MLP helpers (read LDS weight block) ----
template <int OW1, int OB1, int OW2, int OB2>
__device__ __forceinline__ void mlp20(const float* __restrict__ sm,
                                      float tval, const float4* z, float* h2) {
    float h1[20];
#pragma unroll 4
    for (int o = 0; o < 20; ++o) {
        const int ro = OW1 + o * 68;
        float a = sm[OB1 + o] + tval * sm[ro];
        const float4* wr = reinterpret_cast<const float4*>(&sm[ro + 4]);
#pragma unroll
        for (int v = 0; v < 16; ++v) {
            float4 w4 = wr[v];
            a += z[v].x * w4.x + z[v].y * w4.y + z[v].z * w4.z + z[v].w * w4.w;
        }
        h1[o] = fast_sigmoid(a);
    }
#pragma unroll 4
    for (int o = 0; o < 20; ++o) {
        float a = sm[OB2 + o];
        const float4* wr = reinterpret_cast<const float4*>(&sm[OW2 + o * 20]);
#pragma unroll
        for (int v = 0; v < 5; ++v) {
            float4 w4 = wr[v];
            a += h1[4*v+0]*w4.x + h1[4*v+1]*w4.y + h1[4*v+2]*w4.z + h1[4*v+3]*w4.w;
        }
        h2[o] = fast_sigmoid(a);
    }
}

template <int OW3, int OB3, int OCWT>
__device__ __forceinline__ void final64(const float* __restrict__ sm,
                                        const float* h2, float* oacc) {
#pragma unroll 2
    for (int o = 0; o < 64; ++o) {
        float a = sm[OB3 + o];
        const float4* wr = reinterpret_cast<const float4*>(&sm[OW3 + o * 20]);
#pragma unroll
        for (int v = 0; v < 5; ++v) {
            float4 w4 = wr[v];
            a += h2[4*v+0]*w4.x + h2[4*v+1]*w4.y + h2[4*v+2]*w4.z + h2[4*v+3]*w4.w;
        }
        float s = fast_sigmoid(a);
        const float4* cr = reinterpret_cast<const float4*>(&sm[OCWT + o * 64]);
#pragma unroll
        for (int v = 0; v < 16; ++v) {
            float4 c4 = cr[v];
            oacc[4*v+0] += s * c4.x; oacc[4*v+1] += s * c4.y;
            oacc[4*v+2] += s * c4.z; oacc[4*v+3] += s * c4.w;
        }
    }
}

// ---- K_ALL (cooperative, 257 blocks) ----
// block 0: 4-wave chain (bpermute h-gather) + per-chunk uo rows + release flags.
// blocks 1..256: 1024 rows each: state branch -> counting-sort by ti-chunk ->
//                flag-gated ctrl branch (overlaps the chain).
#define SMEMF 15600   // floats (62400 B)

__global__ __launch_bounds__(256) void k_all(
    const float* __restrict__ t_in, const float* __restrict__ x_in,
    const float* __restrict__ i2h_w, const float* __restrict__ h2o_w,
    const float* __restrict__ pre_i, const float* __restrict__ pre_o,
    const float* __restrict__ wp, float* __restrict__ uo,
    int* __restrict__ flags, float* __restrict__ out, int B) {
    __shared__ float smem[SMEMF];
    const int tid = threadIdx.x;
    const int bid = blockIdx.x;

    if (bid == 0) {
        __builtin_amdgcn_s_setprio(3);
        float* pre2 = smem;            // [2][4096]
        float* hs   = smem + 8192;     // [64][64] h BEFORE each step of chunk
        float* part = smem + 12288;    // [2][4][64]
        const int lane = tid & 63;
        const int wv = tid >> 6;

        float wih[16];
#pragma unroll
        for (int t2 = 0; t2 < 16; ++t2) wih[t2] = i2h_w[lane * 72 + 8 + 16 * wv + t2];
        float who[64];
#pragma unroll
        for (int m = 0; m < 64; ++m) who[m] = h2o_w[lane * 72 + 8 + m];
        int bpa[16];
#pragma unroll
        for (int t2 = 0; t2 < 16; ++t2) bpa[t2] = (16 * wv + t2) * 4;

        {   // stage pre chunk 0
            const float4* pg = reinterpret_cast<const float4*>(pre_i);
            float4* pd = reinterpret_cast<float4*>(pre2);
#pragma unroll
            for (int j = 0; j < 4; ++j) pd[tid * 4 + j] = pg[tid * 4 + j];
        }
        __syncthreads();
        float h = 0.0f;
        float pnext = (wv == 0) ? pre2[lane] : 0.0f;
        float4 pl0, pl1, pl2, pl3;

        for (int c = 0; c < NCHUNK; ++c) {
            const int cb = c & 1;
            const float* pre_c = pre2 + cb * 4096;
            if (c + 1 < NCHUNK) {   // issue next-chunk loads (in flight all chunk)
                const float4* pg = reinterpret_cast<const float4*>(pre_i + (c + 1) * 4096);
                pl0 = pg[tid*4+0]; pl1 = pg[tid*4+1]; pl2 = pg[tid*4+2]; pl3 = pg[tid*4+3];
            }
            for (int s = 0; s < CHUNK; ++s) {
                const int pp = s & 1;
                float pcur = pnext;
                int hb = __float_as_int(h);
                float hj[16];
#pragma unroll
                for (int t2 = 0; t2 < 16; ++t2)
                    hj[t2] = __int_as_float(__builtin_amdgcn_ds_bpermute(bpa[t2], hb));
                float a0 = (wv == 0) ? pcur : 0.0f, a1 = 0.0f, a2 = 0.0f, a3 = 0.0f;
#pragma unroll
                for (int t2 = 0; t2 < 16; t2 += 4) {
                    a0 += wih[t2+0] * hj[t2+0];
                    a1 += wih[t2+1] * hj[t2+1];
                    a2 += wih[t2+2] * hj[t2+2];
                    a3 += wih[t2+3] * hj[t2+3];
                }
                part[pp * 256 + wv * 64 + lane] = (a0 + a1) + (a2 + a3);
                if (wv == 0) {
                    hs[s * 64 + lane] = h;                       // carry before step s
                    pnext = pre_c[((s + 1) & 63) * 64 + lane];   // prefetch (s=63 dead)
                }
                __syncthreads();
                float p0 = part[pp * 256 +   0 + lane];
                float p1 = part[pp * 256 +  64 + lane];
                float p2 = part[pp * 256 + 128 + lane];
                float p3 = part[pp * 256 + 192 + lane];
                h = fast_tanh((p0 + p1) + (p2 + p3));
            }
            if (c + 1 < NCHUNK) {   // publish staged pre for next chunk
                float4* pd = reinterpret_cast<float4*>(pre2 + ((c + 1) & 1) * 4096);
                pd[tid*4+0] = pl0; pd[tid*4+1] = pl1; pd[tid*4+2] = pl2; pd[tid*4+3] = pl3;
            }
            {   // uo rows for this chunk: wave wv does rows c*64+wv*16+rr
                float preg[16];
#pragma unroll
                for (int rr = 0; rr < 16; ++rr)
                    preg[rr] = pre_o[(c * 64 + wv * 16 + rr) * 64 + lane];
#pragma unroll 2
                for (int rr = 0; rr < 16; ++rr) {
                    const float4* h4 = reinterpret_cast<const float4*>(hs + (wv * 16 + rr) * 64);
                    float acc = preg[rr];
#pragma unroll
                    for (int v = 0; v < 16; ++v) {
                        float4 hv = h4[v];
                        acc += who[4*v+0]*hv.x + who[4*v+1]*hv.y
                             + who[4*v+2]*hv.z + who[4*v+3]*hv.w;
                    }
                    uo[(c * 64 + wv * 16 + rr) * 64 + lane] = fast_tanh(acc);
                }
            }
            __syncthreads();   // drains uo stores + publishes pre2[next]
            if (tid == 0)
                __hip_atomic_store(&flags[c], 1, __ATOMIC_RELEASE, __HIP_MEMORY_SCOPE_AGENT);
            if (wv == 0 && c + 1 < NCHUNK) pnext = pre2[((c + 1) & 1) * 4096 + lane];
        }
        return;
    }

    // ---- batch blocks: 1024 rows each ----
    {
        float4* s4 = reinterpret_cast<float4*>(smem);
        const float4* w4 = reinterpret_cast<const float4*>(wp);
        for (int idx = tid; idx < L_TOT / 4; idx += 256) s4[idx] = w4[idx];
    }
    __syncthreads();

    const int ib = bid - 1;           // 0..255
    const int r0 = ib << 10;
    const int r1 = r0 + 1024;

    // Phase A: state branch, out[r] = cb + state contribution
    for (int r = r0 + tid; r < r1; r += 256) {
        float tval = t_in[r];
        float4 z[16];
        const float4* xp = reinterpret_cast<const float4*>(x_in + (size_t)r * 64);
#pragma unroll
        for (int v = 0; v < 16; ++v) z[v] = xp[v];
        float h2[20];
        mlp20<L_XW1, L_XB1, L_XW2, L_XB2>(smem, tval, z, h2);
        float oacc[64];
        {
            const float4* cbp = reinterpret_cast<const float4*>(&smem[L_CB]);
#pragma unroll
            for (int v = 0; v < 16; ++v) {
                float4 c4 = cbp[v];
                oacc[4*v+0] = c4.x; oacc[4*v+1] = c4.y;
                oacc[4*v+2] = c4.z; oacc[4*v+3] = c4.w;
            }
        }
        final64<L_XW3, L_XB3, L_CWT>(smem, h2, oacc);
        float4* op = reinterpret_cast<float4*>(out + (size_t)r * 64);
#pragma unroll
        for (int v = 0; v < 16; ++v) {
            float4 f;
            f.x = oacc[4*v+0]; f.y = oacc[4*v+1];
            f.z = oacc[4*v+2]; f.w = oacc[4*v+3];
            op[v] = f;
        }
    }

    // Phase B: local counting sort of own rows by ti-chunk
    int* order = (int*)&smem[14544];   // 1024
    int* hist  = (int*)&smem[15568];   // 16
    int* basep = (int*)&smem[15584];   // 16
    if (tid < 16) hist[tid] = 0;
    __syncthreads();
    for (int r = r0 + tid; r < r1; r += 256) {
        int ti = min((int)(t_in[r] * 1024.0f), 1023);
        atomicAdd(&hist[ti >> 6], 1);
    }
    __syncthreads();
    if (tid == 0) {
        int acc = 0;
#pragma unroll
        for (int k = 0; k < 16; ++k) { basep[k] = acc; acc += hist[k]; hist[k] = basep[k]; }
    }
    __syncthreads();
    for (int r = r0 + tid; r < r1; r += 256) {
        int ti = min((int)(t_in[r] * 1024.0f), 1023);
        int pos = atomicAdd(&hist[ti >> 6], 1);
        order[pos] = r;
    }
    __syncthreads();

    // Phase C: control branch, gated per-chunk on flags
    for (int it = 0; it < 4; ++it) {
        int p = tid + it * 256;
        int row = order[p];
        float tval = t_in[row];
        int ti = min((int)(tval * 1024.0f), 1023);
        int m = ti >> 6;
#pragma unroll
        for (int off = 32; off >= 1; off >>= 1) m = max(m, __shfl_xor(m, off));
        while (__hip_atomic_load(&flags[m], __ATOMIC_ACQUIRE, __HIP_MEMORY_SCOPE_AGENT) == 0)
            __builtin_amdgcn_s_sleep(8);
        float4 z[16];
        const float4* ep = reinterpret_cast<const float4*>(uo + ti * 64);
#pragma unroll
        for (int v = 0; v < 16; ++v) z[v] = ep[v];
        float h2[20];
        mlp20<L_UW1, L_UB1, L_UW2, L_UB2>(smem, tval, z, h2);
        float oacc[64];
        float4* op = reinterpret_cast<float4*>(out + (size_t)row * 64);
#pragma unroll
        for (int v = 0; v < 16; ++v) {
            float4 f = op[v];
            oacc[4*v+0] = f.x; oacc[4*v+1] = f.y;
            oacc[4*v+2] = f.z; oacc[4*v+3] = f.w;
        }
        final64<L_UW3, L_UB3, L_CWT + 64 * 64>(smem, h2, oacc);
#pragma unroll
        for (int v = 0; v < 16; ++v) {
            float4 f;
            f.x = oacc[4*v+0]; f.y = oacc[4*v+1];
            f.z = oacc[4*v+2]; f.w = oacc[4*v+3];
            op[v] = f;
        }
    }
}

// ======== FALLBACK PATH (proven round-9 kernels), used if coop launch fails ========
#define SMEM9 16960

__global__ __launch_bounds__(256) void k_main_r9(
    const float* __restrict__ t_in, const float* __restrict__ x_in,
    const float* __restrict__ i2h_w,
    const float* __restrict__ pre_i,
    const float* __restrict__ wp,
    float* __restrict__ hseq, float* __restrict__ out) {
    __shared__ float smem[SMEM9];
    const int tid = threadIdx.x;
    const int bid = blockIdx.x;

    if (bid == 0) {
        float* pre2 = smem;            // [2][4096]
        float* hs2  = smem + 8192;     // [2][4096]
        float* hq   = smem + 16384;    // [4][16]
        float* part = smem + 16448;    // [2][4][64]
        const int lane = tid & 63;
        const int wv = tid >> 6;

        float wih[16];
#pragma unroll
        for (int j = 0; j < 16; ++j) wih[j] = i2h_w[lane * 72 + 8 + 16 * wv + j];

        {
            const float4* pg = reinterpret_cast<const float4*>(pre_i);
            float4* pd = reinterpret_cast<float4*>(pre2);
#pragma unroll
            for (int j = 0; j < 4; ++j) pd[tid * 4 + j] = pg[tid * 4 + j];
        }
        float h = 0.0f;
        __syncthreads();

        float4 pl0, pl1, pl2, pl3;
        for (int c = 0; c < NCHUNK; ++c) {
            const int cb = c & 1;
            const float* pre_c = pre2 + cb * 4096;
            float* hs_c = hs2 + cb * 4096;
            if (c + 1 < NCHUNK) {
                const float4* pg = reinterpret_cast<const float4*>(pre_i + (c + 1) * 4096);
                pl0 = pg[tid*4+0]; pl1 = pg[tid*4+1]; pl2 = pg[tid*4+2]; pl3 = pg[tid*4+3];
            }
            if (c >= 1) {
                const float4* hsrc = reinterpret_cast<const float4*>(hs2 + (cb ^ 1) * 4096);
                float4* hdst = reinterpret_cast<float4*>(hseq + (c - 1) * 4096);
                float4 s0 = hsrc[tid*4+0], s1 = hsrc[tid*4+1], s2 = hsrc[tid*4+2], s3 = hsrc[tid*4+3];
                hdst[tid*4+0] = s0; hdst[tid*4+1] = s1; hdst[tid*4+2] = s2; hdst[tid*4+3] = s3;
            }
#pragma unroll 2
            for (int s = 0; s < CHUNK; ++s) {
                const int pp = s & 1;
                if (wv == 0) hs_c[s * 64 + lane] = h;
                if ((lane >> 4) == wv) hq[wv * 16 + (lane & 15)] = h;
                float a0 = (wv == 0) ? pre_c[s * 64 + lane] : 0.0f;
                const float4* hb = reinterpret_cast<const float4*>(hq + wv * 16);
                float4 b0 = hb[0], b1 = hb[1], b2 = hb[2], b3 = hb[3];
                float a1 = 0.0f, a2 = 0.0f, a3 = 0.0f;
                a0 += wih[ 0]*b0.x + wih[ 1]*b0.y + wih[ 2]*b0.z + wih[ 3]*b0.w;
                a1 += wih[ 4]*b1.x + wih[ 5]*b1.y + wih[ 6]*b1.z + wih[ 7]*b1.w;
                a2 += wih[ 8]*b2.x + wih[ 9]*b2.y + wih[10]*b2.z + wih[11]*b2.w;
                a3 += wih[12]*b3.x + wih[13]*b3.y + wih[14]*b3.z + wih[15]*b3.w;
                part[pp * 256 + wv * 64 + lane] = (a0 + a1) + (a2 + a3);
                __syncthreads();
                float p0 = part[pp * 256 +   0 + lane];
                float p1 = part[pp * 256 +  64 + lane];
                float p2 = part[pp * 256 + 128 + lane];
                float p3 = part[pp * 256 + 192 + lane];
                h = fast_tanh((p0 + p1) + (p2 + p3));
            }
            if (c + 1 < NCHUNK) {
                float4* pd = reinterpret_cast<float4*>(pre2 + ((c + 1) & 1) * 4096);
                pd[tid*4+0] = pl0; pd[tid*4+1] = pl1; pd[tid*4+2] = pl2; pd[tid*4+3] = pl3;
            }
            __syncthreads();
        }
        {
            const float4* hsrc = reinterpret_cast<const float4*>(hs2 + ((NCHUNK - 1) & 1) * 4096);
            float4* hdst = reinterpret_cast<float4*>(hseq + (NCHUNK - 1) * 4096);
#pragma unroll
            for (int j = 0; j < 4; ++j) hdst[tid * 4 + j] = hsrc[tid * 4 + j];
        }
        return;
    }

    {
        float4* s4 = reinterpret_cast<float4*>(smem);
        const float4* w4 = reinterpret_cast<const float4*>(wp);
        for (int idx = tid; idx < L_TOT / 4; idx += 256) s4[idx] = w4[idx];
    }
    __syncthreads();

    const int r = (bid - 1) * 256 + tid;
    float tval = t_in[r];
    float4 z[16];
    const float4* xp = reinterpret_cast<const float4*>(x_in + (size_t)r * 64);
#pragma unroll
    for (int v = 0; v < 16; ++v) z[v] = xp[v];

    float h2[20];
    mlp20<L_XW1, L_XB1, L_XW2, L_XB2>(smem, tval, z, h2);

    float oacc[64];
    {
        const float4* cbp = reinterpret_cast<const float4*>(&smem[L_CB]);
#pragma unroll
        for (int v = 0; v < 16; ++v) {
            float4 c4 = cbp[v];
            oacc[4*v+0] = c4.x; oacc[4*v+1] = c4.y;
            oacc[4*v+2] = c4.z; oacc[4*v+3] = c4.w;
        }
    }
    final64<L_XW3, L_XB3, L_CWT>(smem, h2, oacc);

    float4* op = reinterpret_cast<float4*>(out + (size_t)r * 64);
#pragma unroll
    for (int v = 0; v < 16; ++v) {
        float4 f;
        f.x = oacc[4*v+0]; f.y = oacc[4*v+1];
        f.z = oacc[4*v+2]; f.w = oacc[4*v+3];
        op[v] = f;
    }
}

__global__ __launch_bounds__(64) void k_rnn_out(
    const float* __restrict__ h2o_w,
    const float* __restrict__ pre_o,
    const float* __restrict__ hseq,
    float* __restrict__ uout) {
    int k = blockIdx.x, i = threadIdx.x;
    __shared__ float hk[64];
    hk[i] = hseq[k * 64 + i];
    __syncthreads();
    float acc = pre_o[k * 64 + i];
#pragma unroll
    for (int m = 0; m < 64; ++m) acc += h2o_w[i * 72 + 8 + m] * hk[m];
    uout[k * 64 + i] = fast_tanh(acc);
}

__global__ __launch_bounds__(256) void k_ctrl(
    const float* __restrict__ t_in, const float* __restrict__ uo,
    const float* __restrict__ wp, float* __restrict__ out) {
    __shared__ float sm[L_TOT];
    const int tid = threadIdx.x;
    {
        float4* s4 = reinterpret_cast<float4*>(sm);
        const float4* w4 = reinterpret_cast<const float4*>(wp);
        for (int idx = tid; idx < L_TOT / 4; idx += 256) s4[idx] = w4[idx];
    }
    __syncthreads();

    const int r = blockIdx.x * 256 + tid;
    float tval = t_in[r];
    int ti = min((int)(tval * 1024.0f), 1023);
    float4 z[16];
    const float4* ep = reinterpret_cast<const float4*>(uo + ti * 64);
#pragma unroll
    for (int v = 0; v < 16; ++v) z[v] = ep[v];

    float h2[20];
    mlp20<L_UW1, L_UB1, L_UW2, L_UB2>(sm, tval, z, h2);

    float oacc[64];
    float4* op = reinterpret_cast<float4*>(out + (size_t)r * 64);
#pragma unroll
    for (int v = 0; v < 16; ++v) {
        float4 f = op[v];
        oacc[4*v+0] = f.x; oacc[4*v+1] = f.y;
        oacc[4*v+2] = f.z; oacc[4*v+3] = f.w;
    }
    final64<L_UW3, L_UB3, L_CWT + 64 * 64>(sm, h2, oacc);
#pragma unroll
    for (int v = 0; v < 16; ++v) {
        float4 f;
        f.x = oacc[4*v+0]; f.y = oacc[4*v+1];
        f.z = oacc[4*v+2]; f.w = oacc[4*v+3];
        op[v] = f;
    }
}

extern "C" void kernel_launch(void* const* d_in, const int* in_sizes, int n_in,
                              void* d_out, int out_size, void* d_ws, size_t ws_size,
                              hipStream_t stream) {
    const float* t     = (const float*)d_in[0];
    const float* x     = (const float*)d_in[1];
    const float* u     = (const float*)d_in[2];
    const float* i2h_w = (const float*)d_in[3];
    const float* i2h_b = (const float*)d_in[4];
    const float* h2o_w = (const float*)d_in[5];
    const float* h2o_b = (const float*)d_in[6];
    const float* xw1 = (const float*)d_in[7];  const float* xb1 = (const float*)d_in[8];
    const float* xw2 = (const float*)d_in[9];  const float* xb2 = (const float*)d_in[10];
    const float* xw3 = (const float*)d_in[11]; const float* xb3 = (const float*)d_in[12];
    const float* uw1 = (const float*)d_in[13]; const float* ub1 = (const float*)d_in[14];
    const float* uw2 = (const float*)d_in[15]; const float* ub2 = (const float*)d_in[16];
    const float* uw3 = (const float*)d_in[17]; const float* ub3 = (const float*)d_in[18];
    const float* cw  = (const float*)d_in[19]; const float* cb  = (const float*)d_in[20];
    float* out = (float*)d_out;

    float* ws = (float*)d_ws;
    float* pre_i = ws;                 // [0,      65536)
    float* pre_o = ws + 65536;         // [65536, 131072)
    float* uo    = ws + 131072;        // [131072,196608)
    float* wp    = ws + 196608;        // [196608,211152)
    int*   flags = (int*)(ws + 211152);// 16 ints
    float* hseq  = ws;                 // fallback only: aliases pre_i (disjoint chunk lifetimes)

    int Bv = in_sizes[0];              // 262144

    hipLaunchKernelGGL(k_repack, dim3((L_TOT + 255) / 256), dim3(256), 0, stream,
                       xw1, uw1, xw2, uw2, xw3, uw3, cw,
                       xb1, xb2, ub1, ub2, xb3, ub3, cb, wp);
    hipLaunchKernelGGL(k_rnn_pre, dim3(256), dim3(256), 0, stream,
                       u, i2h_w, i2h_b, h2o_w, h2o_b, pre_i, pre_o);
    hipMemsetAsync(flags, 0, 16 * sizeof(int), stream);

    void* kargs[] = { (void*)&t, (void*)&x, (void*)&i2h_w, (void*)&h2o_w,
                      (void*)&pre_i, (void*)&pre_o, (void*)&wp, (void*)&uo,
                      (void*)&flags, (void*)&out, (void*)&Bv };
    hipError_t cerr = hipLaunchCooperativeKernel((const void*)k_all, dim3(NBLK),
                                                 dim3(256), kargs, 0, stream);
    if (cerr != hipSuccess) {
        // fallback: proven round-9 sequence (chain + hidden state branch, then tail)
        hipLaunchKernelGGL(k_main_r9, dim3(1 + Bv / 256), dim3(256), 0, stream,
                           t, x, i2h_w, pre_i, wp, hseq, out);
        hipLaunchKernelGGL(k_rnn_out, dim3(T_SEQ), dim3(64), 0, stream,
                           h2o_w, pre_o, hseq, uo);
        hipLaunchKernelGGL(k_ctrl, dim3(Bv / 256), dim3(256), 0, stream,
                           t, uo, wp, out);
    }
}

// Round 12
// 567.481 us; speedup vs baseline: 1.2058x; 1.2058x over previous
//
#include <hip/hip_runtime.h>
#include <hip/hip_bf16.h>

#define T_SEQ 1024
#define CHUNK 64
#define NCHUNK 16
#define NBLK 256   // coop: block 0 = chain, 1 = uo worker, 2..255 = batch (1 block/CU)

__device__ __forceinline__ float fast_sigmoid(float x) {
    return 1.0f / (1.0f + __expf(-x));
}
__device__ __forceinline__ float fast_tanh(float x) {
    float e = __expf(2.0f * x);
    return 1.0f - 2.0f / (e + 1.0f);
}

// K1: precompute u-dependent parts of both RNN linears (+bias)
__global__ __launch_bounds__(256) void k_rnn_pre(
    const float* __restrict__ u,
    const float* __restrict__ i2h_w, const float* __restrict__ i2h_b,
    const float* __restrict__ h2o_w, const float* __restrict__ h2o_b,
    float* __restrict__ pre_i, float* __restrict__ pre_o) {
    int idx = blockIdx.x * 256 + threadIdx.x;   // 0..65535
    int k = idx >> 6, i = idx & 63;
    float a = i2h_b[i], b = h2o_b[i];
#pragma unroll
    for (int c = 0; c < 8; ++c) {
        float uv = u[k * 8 + c];
        a += uv * i2h_w[i * 72 + c];
        b += uv * h2o_w[i * 72 + c];
    }
    pre_i[idx] = a;
    pre_o[idx] = b;
}

// ---- packed weight block layout (floats), produced by k_repack ----
#define L_XW1 0
#define L_UW1 1360
#define L_XW2 2720
#define L_UW2 3120
#define L_XW3 3520
#define L_UW3 4800
#define L_CWT 6080
#define L_XB1 14272
#define L_XB2 14292
#define L_UB1 14312
#define L_UB2 14332
#define L_XB3 14352
#define L_UB3 14416
#define L_CB  14480
#define L_TOT 14544   // 58176 bytes

__global__ __launch_bounds__(256) void k_repack(
    const float* __restrict__ xw1, const float* __restrict__ uw1,
    const float* __restrict__ xw2, const float* __restrict__ uw2,
    const float* __restrict__ xw3, const float* __restrict__ uw3,
    const float* __restrict__ cw,
    const float* __restrict__ xb1, const float* __restrict__ xb2,
    const float* __restrict__ ub1, const float* __restrict__ ub2,
    const float* __restrict__ xb3, const float* __restrict__ ub3,
    const float* __restrict__ cb, float* __restrict__ wp) {
    int i = blockIdx.x * 256 + threadIdx.x;
    if (i >= L_TOT) return;
    float v = 0.0f;
    if (i < 1360) {
        int o = i / 68, c = i - o * 68;
        if (c == 0) v = xw1[o * 65];
        else if (c >= 4) v = xw1[o * 65 + c - 3];
    } else if (i < 2720) {
        int j = i - 1360; int o = j / 68, c = j - o * 68;
        if (c == 0) v = uw1[o * 65];
        else if (c >= 4) v = uw1[o * 65 + c - 3];
    } else if (i < 3120) v = xw2[i - 2720];
    else if (i < 3520) v = uw2[i - 3120];
    else if (i < 4800) v = xw3[i - 3520];
    else if (i < 6080) v = uw3[i - 4800];
    else if (i < 14272) {
        int j = i - 6080; int row = j >> 6, s = j & 63;
        v = cw[s * 128 + row];
    }
    else if (i < 14292) v = xb1[i - 14272];
    else if (i < 14312) v = xb2[i - 14292];
    else if (i < 14332) v = ub1[i - 14312];
    else if (i < 14352) v = ub2[i - 14332];
    else if (i < 14416) v = xb3[i - 14352];
    else if (i < 14480) v = ub3[i - 14416];
    else v = cb[i - 14480];
    wp[i] = v;
}

// ---- MLP helpers (read LDS weight block) ----
template <int OW1, int OB1, int OW2, int OB2>
__device__ __forceinline__ void mlp20(const float* __restrict__ sm,
                                      float tval, const float4* z, float* h2) {
    float h1[20];
#pragma unroll 4
    for (int o = 0; o < 20; ++o) {
        const int ro = OW1 + o * 68;
        float a = sm[OB1 + o] + tval * sm[ro];
        const float4* wr = reinterpret_cast<const float4*>(&sm[ro + 4]);
#pragma unroll
        for (int v = 0; v < 16; ++v) {
            float4 w4 = wr[v];
            a += z[v].x * w4.x + z[v].y * w4.y + z[v].z * w4.z + z[v].w * w4.w;
        }
        h1[o] = fast_sigmoid(a);
    }
#pragma unroll 4
    for (int o = 0; o < 20; ++o) {
        float a = sm[OB2 + o];
        const float4* wr = reinterpret_cast<const float4*>(&sm[OW2 + o * 20]);
#pragma unroll
        for (int v = 0; v < 5; ++v) {
            float4 w4 = wr[v];
            a += h1[4*v+0]*w4.x + h1[4*v+1]*w4.y + h1[4*v+2]*w4.z + h1[4*v+3]*w4.w;
        }
        h2[o] = fast_sigmoid(a);
    }
}

template <int OW3, int OB3, int OCWT>
__device__ __forceinline__ void final64(const float* __restrict__ sm,
                                        const float* h2, float* oacc) {
#pragma unroll 2
    for (int o = 0; o < 64; ++o) {
        float a = sm[OB3 + o];
        const float4* wr = reinterpret_cast<const float4*>(&sm[OW3 + o * 20]);
#pragma unroll
        for (int v = 0; v < 5; ++v) {
            float4 w4 = wr[v];
            a += h2[4*v+0]*w4.x + h2[4*v+1]*w4.y + h2[4*v+2]*w4.z + h2[4*v+3]*w4.w;
        }
        float s = fast_sigmoid(a);
        const float4* cr = reinterpret_cast<const float4*>(&sm[OCWT + o * 64]);
#pragma unroll
        for (int v = 0; v < 16; ++v) {
            float4 c4 = cr[v];
            oacc[4*v+0] += s * c4.x; oacc[4*v+1] += s * c4.y;
            oacc[4*v+2] += s * c4.z; oacc[4*v+3] += s * c4.w;
        }
    }
}

// ---- K_ALL (cooperative, 256 blocks, 86 KB LDS forces 1 block/CU) ----
// block 0: chain only (bpermute h-gather); flushes hseq per chunk, releases flag1.
// block 1: uo worker: waits flag1[c], computes uo rows for chunk c, releases flag2.
// blocks 2..255: batch: state branch -> counting sort by ti-chunk -> flag2-gated ctrl.
#define SMEMF 21504   // 86016 B > 160KB/2 -> exactly 1 block per CU

__global__ __launch_bounds__(256) void k_all(
    const float* __restrict__ t_in, const float* __restrict__ x_in,
    const float* __restrict__ i2h_w, const float* __restrict__ h2o_w,
    const float* __restrict__ pre_i, const float* __restrict__ pre_o,
    const float* __restrict__ wp, float* __restrict__ uo,
    float* __restrict__ hseq,
    int* __restrict__ flag1, int* __restrict__ flag2,
    float* __restrict__ out, int B) {
    __shared__ float smem[SMEMF];
    const int tid = threadIdx.x;
    const int bid = blockIdx.x;

    if (bid == 0) {
        // ---- chain block (dedicated CU) ----
        float* pre2 = smem;            // [2][4096]
        float* hs   = smem + 8192;     // [64][64] h BEFORE each step
        float* part = smem + 12288;    // [2][4][64]
        const int lane = tid & 63;
        const int wv = tid >> 6;

        float wih[16];
#pragma unroll
        for (int t2 = 0; t2 < 16; ++t2) wih[t2] = i2h_w[lane * 72 + 8 + 16 * wv + t2];
        int bpa[16];
#pragma unroll
        for (int t2 = 0; t2 < 16; ++t2) bpa[t2] = (16 * wv + t2) * 4;

        {   // stage pre chunk 0
            const float4* pg = reinterpret_cast<const float4*>(pre_i);
            float4* pd = reinterpret_cast<float4*>(pre2);
#pragma unroll
            for (int j = 0; j < 4; ++j) pd[tid * 4 + j] = pg[tid * 4 + j];
        }
        __syncthreads();
        float h = 0.0f;
        float pnext = (wv == 0) ? pre2[lane] : 0.0f;
        float4 pl0, pl1, pl2, pl3;

        for (int c = 0; c < NCHUNK; ++c) {
            const int cb = c & 1;
            const float* pre_c = pre2 + cb * 4096;
            if (c + 1 < NCHUNK) {   // issue next-chunk loads (in flight)
                const float4* pg = reinterpret_cast<const float4*>(pre_i + (c + 1) * 4096);
                pl0 = pg[tid*4+0]; pl1 = pg[tid*4+1]; pl2 = pg[tid*4+2]; pl3 = pg[tid*4+3];
            }
            for (int s = 0; s < CHUNK; ++s) {
                const int pp = s & 1;
                float pcur = pnext;
                int hb = __float_as_int(h);
                float hj[16];
#pragma unroll
                for (int t2 = 0; t2 < 16; ++t2)
                    hj[t2] = __int_as_float(__builtin_amdgcn_ds_bpermute(bpa[t2], hb));
                if (wv == 0) {
                    hs[s * 64 + lane] = h;                       // carry before step s
                    pnext = pre_c[((s + 1) & 63) * 64 + lane];   // prefetch (s=63 dead)
                }
                float a0 = (wv == 0) ? pcur : 0.0f, a1 = 0.0f, a2 = 0.0f, a3 = 0.0f;
#pragma unroll
                for (int t2 = 0; t2 < 16; t2 += 4) {
                    a0 += wih[t2+0] * hj[t2+0];
                    a1 += wih[t2+1] * hj[t2+1];
                    a2 += wih[t2+2] * hj[t2+2];
                    a3 += wih[t2+3] * hj[t2+3];
                }
                part[pp * 256 + wv * 64 + lane] = (a0 + a1) + (a2 + a3);
                __syncthreads();
                float p0 = part[pp * 256 +   0 + lane];
                float p1 = part[pp * 256 +  64 + lane];
                float p2 = part[pp * 256 + 128 + lane];
                float p3 = part[pp * 256 + 192 + lane];
                h = fast_tanh((p0 + p1) + (p2 + p3));
            }
            {   // flush this chunk's h history to global hseq
                const float4* hsrc = reinterpret_cast<const float4*>(hs);
                float4* hdst = reinterpret_cast<float4*>(hseq + c * 4096);
#pragma unroll
                for (int j = 0; j < 4; ++j) hdst[tid * 4 + j] = hsrc[tid * 4 + j];
            }
            if (c + 1 < NCHUNK) {   // publish staged pre for next chunk
                float4* pd = reinterpret_cast<float4*>(pre2 + ((c + 1) & 1) * 4096);
                pd[tid*4+0] = pl0; pd[tid*4+1] = pl1; pd[tid*4+2] = pl2; pd[tid*4+3] = pl3;
            }
            __syncthreads();   // drains hseq stores (vmcnt0) + publishes pre2
            if (tid == 0)
                __hip_atomic_store(&flag1[c], 1, __ATOMIC_RELEASE, __HIP_MEMORY_SCOPE_AGENT);
            if (wv == 0 && c + 1 < NCHUNK) pnext = pre2[((c + 1) & 1) * 4096 + lane];
        }
        return;
    }

    if (bid == 1) {
        // ---- uo worker block ----
        float* hk = smem;              // [64][64]
        const int lane = tid & 63;
        const int wv = tid >> 6;
        float who[64];
#pragma unroll
        for (int m = 0; m < 64; ++m) who[m] = h2o_w[lane * 72 + 8 + m];

        for (int c = 0; c < NCHUNK; ++c) {
            while (__hip_atomic_load(&flag1[c], __ATOMIC_ACQUIRE, __HIP_MEMORY_SCOPE_AGENT) == 0)
                __builtin_amdgcn_s_sleep(8);
            {   // copy hseq chunk c to LDS
                const float4* hg = reinterpret_cast<const float4*>(hseq + c * 4096);
                float4* hd = reinterpret_cast<float4*>(hk);
#pragma unroll
                for (int j = 0; j < 4; ++j) hd[tid * 4 + j] = hg[tid * 4 + j];
            }
            __syncthreads();
            float preg[16];
#pragma unroll
            for (int rr = 0; rr < 16; ++rr)
                preg[rr] = pre_o[(c * 64 + wv * 16 + rr) * 64 + lane];
#pragma unroll 2
            for (int rr = 0; rr < 16; ++rr) {
                const float4* h4 = reinterpret_cast<const float4*>(hk + (wv * 16 + rr) * 64);
                float acc = preg[rr];
#pragma unroll
                for (int v = 0; v < 16; ++v) {
                    float4 hv = h4[v];
                    acc += who[4*v+0]*hv.x + who[4*v+1]*hv.y
                         + who[4*v+2]*hv.z + who[4*v+3]*hv.w;
                }
                uo[(c * 64 + wv * 16 + rr) * 64 + lane] = fast_tanh(acc);
            }
            __syncthreads();   // drains uo stores; protects hk WAR
            if (tid == 0)
                __hip_atomic_store(&flag2[c], 1, __ATOMIC_RELEASE, __HIP_MEMORY_SCOPE_AGENT);
        }
        return;
    }

    // ---- batch blocks (bid 2..255): uneven split of B rows over 254 blocks ----
    {
        float4* s4 = reinterpret_cast<float4*>(smem);
        const float4* w4 = reinterpret_cast<const float4*>(wp);
        for (int idx = tid; idx < L_TOT / 4; idx += 256) s4[idx] = w4[idx];
    }
    __syncthreads();

    const int ib = bid - 2;                       // 0..253
    const int r0 = ib * 1032 + min(ib, 16);
    const int count = 1032 + (ib < 16 ? 1 : 0);
    const int r1 = r0 + count;

    // Phase A: state branch, out[r] = cb + state contribution
    for (int r = r0 + tid; r < r1; r += 256) {
        float tval = t_in[r];
        float4 z[16];
        const float4* xp = reinterpret_cast<const float4*>(x_in + (size_t)r * 64);
#pragma unroll
        for (int v = 0; v < 16; ++v) z[v] = xp[v];
        float h2[20];
        mlp20<L_XW1, L_XB1, L_XW2, L_XB2>(smem, tval, z, h2);
        float oacc[64];
        {
            const float4* cbp = reinterpret_cast<const float4*>(&smem[L_CB]);
#pragma unroll
            for (int v = 0; v < 16; ++v) {
                float4 c4 = cbp[v];
                oacc[4*v+0] = c4.x; oacc[4*v+1] = c4.y;
                oacc[4*v+2] = c4.z; oacc[4*v+3] = c4.w;
            }
        }
        final64<L_XW3, L_XB3, L_CWT>(smem, h2, oacc);
        float4* op = reinterpret_cast<float4*>(out + (size_t)r * 64);
#pragma unroll
        for (int v = 0; v < 16; ++v) {
            float4 f;
            f.x = oacc[4*v+0]; f.y = oacc[4*v+1];
            f.z = oacc[4*v+2]; f.w = oacc[4*v+3];
            op[v] = f;
        }
    }

    // Phase B: local counting sort of own rows by ti-chunk
    int* order = (int*)&smem[14544];   // up to 1033
    int* hist  = (int*)&smem[15584];   // 16
    int* basep = (int*)&smem[15600];   // 16
    if (tid < 16) hist[tid] = 0;
    __syncthreads();
    for (int r = r0 + tid; r < r1; r += 256) {
        int ti = min((int)(t_in[r] * 1024.0f), 1023);
        atomicAdd(&hist[ti >> 6], 1);
    }
    __syncthreads();
    if (tid == 0) {
        int acc = 0;
#pragma unroll
        for (int k = 0; k < 16; ++k) { basep[k] = acc; acc += hist[k]; hist[k] = basep[k]; }
    }
    __syncthreads();
    for (int r = r0 + tid; r < r1; r += 256) {
        int ti = min((int)(t_in[r] * 1024.0f), 1023);
        int pos = atomicAdd(&hist[ti >> 6], 1);
        order[pos] = r;
    }
    __syncthreads();

    // Phase C: control branch, gated per-chunk on flag2
    const int niter = (count + 255) >> 8;
    for (int it = 0; it < niter; ++it) {
        int p = tid + it * 256;
        bool act = p < count;
        int row = act ? order[p] : r0;
        float tval = t_in[row];
        int ti = min((int)(tval * 1024.0f), 1023);
        int m = act ? (ti >> 6) : 0;
#pragma unroll
        for (int off = 32; off >= 1; off >>= 1) m = max(m, __shfl_xor(m, off));
        while (__hip_atomic_load(&flag2[m], __ATOMIC_ACQUIRE, __HIP_MEMORY_SCOPE_AGENT) == 0)
            __builtin_amdgcn_s_sleep(8);
        if (act) {
            float4 z[16];
            const float4* ep = reinterpret_cast<const float4*>(uo + ti * 64);
#pragma unroll
            for (int v = 0; v < 16; ++v) z[v] = ep[v];
            float h2[20];
            mlp20<L_UW1, L_UB1, L_UW2, L_UB2>(smem, tval, z, h2);
            float oacc[64];
            float4* op = reinterpret_cast<float4*>(out + (size_t)row * 64);
#pragma unroll
            for (int v = 0; v < 16; ++v) {
                float4 f = op[v];
                oacc[4*v+0] = f.x; oacc[4*v+1] = f.y;
                oacc[4*v+2] = f.z; oacc[4*v+3] = f.w;
            }
            final64<L_UW3, L_UB3, L_CWT + 64 * 64>(smem, h2, oacc);
#pragma unroll
            for (int v = 0; v < 16; ++v) {
                float4 f;
                f.x = oacc[4*v+0]; f.y = oacc[4*v+1];
                f.z = oacc[4*v+2]; f.w = oacc[4*v+3];
                op[v] = f;
            }
        }
    }
}

// ======== FALLBACK PATH (proven round-9 kernels), used if coop launch fails ========
#define SMEM9 16960

__global__ __launch_bounds__(256) void k_main_r9(
    const float* __restrict__ t_in, const float* __restrict__ x_in,
    const float* __restrict__ i2h_w,
    const float* __restrict__ pre_i,
    const float* __restrict__ wp,
    float* __restrict__ hseq, float* __restrict__ out) {
    __shared__ float smem[SMEM9];
    const int tid = threadIdx.x;
    const int bid = blockIdx.x;

    if (bid == 0) {
        float* pre2 = smem;            // [2][4096]
        float* hs2  = smem + 8192;     // [2][4096]
        float* hq   = smem + 16384;    // [4][16]
        float* part = smem + 16448;    // [2][4][64]
        const int lane = tid & 63;
        const int wv = tid >> 6;

        float wih[16];
#pragma unroll
        for (int j = 0; j < 16; ++j) wih[j] = i2h_w[lane * 72 + 8 + 16 * wv + j];

        {
            const float4* pg = reinterpret_cast<const float4*>(pre_i);
            float4* pd = reinterpret_cast<float4*>(pre2);
#pragma unroll
            for (int j = 0; j < 4; ++j) pd[tid * 4 + j] = pg[tid * 4 + j];
        }
        float h = 0.0f;
        __syncthreads();

        float4 pl0, pl1, pl2, pl3;
        for (int c = 0; c < NCHUNK; ++c) {
            const int cb = c & 1;
            const float* pre_c = pre2 + cb * 4096;
            float* hs_c = hs2 + cb * 4096;
            if (c + 1 < NCHUNK) {
                const float4* pg = reinterpret_cast<const float4*>(pre_i + (c + 1) * 4096);
                pl0 = pg[tid*4+0]; pl1 = pg[tid*4+1]; pl2 = pg[tid*4+2]; pl3 = pg[tid*4+3];
            }
            if (c >= 1) {
                const float4* hsrc = reinterpret_cast<const float4*>(hs2 + (cb ^ 1) * 4096);
                float4* hdst = reinterpret_cast<float4*>(hseq + (c - 1) * 4096);
                float4 s0 = hsrc[tid*4+0], s1 = hsrc[tid*4+1], s2 = hsrc[tid*4+2], s3 = hsrc[tid*4+3];
                hdst[tid*4+0] = s0; hdst[tid*4+1] = s1; hdst[tid*4+2] = s2; hdst[tid*4+3] = s3;
            }
#pragma unroll 2
            for (int s = 0; s < CHUNK; ++s) {
                const int pp = s & 1;
                if (wv == 0) hs_c[s * 64 + lane] = h;
                if ((lane >> 4) == wv) hq[wv * 16 + (lane & 15)] = h;
                float a0 = (wv == 0) ? pre_c[s * 64 + lane] : 0.0f;
                const float4* hb = reinterpret_cast<const float4*>(hq + wv * 16);
                float4 b0 = hb[0], b1 = hb[1], b2 = hb[2], b3 = hb[3];
                float a1 = 0.0f, a2 = 0.0f, a3 = 0.0f;
                a0 += wih[ 0]*b0.x + wih[ 1]*b0.y + wih[ 2]*b0.z + wih[ 3]*b0.w;
                a1 += wih[ 4]*b1.x + wih[ 5]*b1.y + wih[ 6]*b1.z + wih[ 7]*b1.w;
                a2 += wih[ 8]*b2.x + wih[ 9]*b2.y + wih[10]*b2.z + wih[11]*b2.w;
                a3 += wih[12]*b3.x + wih[13]*b3.y + wih[14]*b3.z + wih[15]*b3.w;
                part[pp * 256 + wv * 64 + lane] = (a0 + a1) + (a2 + a3);
                __syncthreads();
                float p0 = part[pp * 256 +   0 + lane];
                float p1 = part[pp * 256 +  64 + lane];
                float p2 = part[pp * 256 + 128 + lane];
                float p3 = part[pp * 256 + 192 + lane];
                h = fast_tanh((p0 + p1) + (p2 + p3));
            }
            if (c + 1 < NCHUNK) {
                float4* pd = reinterpret_cast<float4*>(pre2 + ((c + 1) & 1) * 4096);
                pd[tid*4+0] = pl0; pd[tid*4+1] = pl1; pd[tid*4+2] = pl2; pd[tid*4+3] = pl3;
            }
            __syncthreads();
        }
        {
            const float4* hsrc = reinterpret_cast<const float4*>(hs2 + ((NCHUNK - 1) & 1) * 4096);
            float4* hdst = reinterpret_cast<float4*>(hseq + (NCHUNK - 1) * 4096);
#pragma unroll
            for (int j = 0; j < 4; ++j) hdst[tid * 4 + j] = hsrc[tid * 4 + j];
        }
        return;
    }

    {
        float4* s4 = reinterpret_cast<float4*>(smem);
        const float4* w4 = reinterpret_cast<const float4*>(wp);
        for (int idx = tid; idx < L_TOT / 4; idx += 256) s4[idx] = w4[idx];
    }
    __syncthreads();

    const int r = (bid - 1) * 256 + tid;
    float tval = t_in[r];
    float4 z[16];
    const float4* xp = reinterpret_cast<const float4*>(x_in + (size_t)r * 64);
#pragma unroll
    for (int v = 0; v < 16; ++v) z[v] = xp[v];

    float h2[20];
    mlp20<L_XW1, L_XB1, L_XW2, L_XB2>(smem, tval, z, h2);

    float oacc[64];
    {
        const float4* cbp = reinterpret_cast<const float4*>(&smem[L_CB]);
#pragma unroll
        for (int v = 0; v < 16; ++v) {
            float4 c4 = cbp[v];
            oacc[4*v+0] = c4.x; oacc[4*v+1] = c4.y;
            oacc[4*v+2] = c4.z; oacc[4*v+3] = c4.w;
        }
    }
    final64<L_XW3, L_XB3, L_CWT>(smem, h2, oacc);

    float4* op = reinterpret_cast<float4*>(out + (size_t)r * 64);
#pragma unroll
    for (int v = 0; v < 16; ++v) {
        float4 f;
        f.x = oacc[4*v+0]; f.y = oacc[4*v+1];
        f.z = oacc[4*v+2]; f.w = oacc[4*v+3];
        op[v] = f;
    }
}

__global__ __launch_bounds__(64) void k_rnn_out(
    const float* __restrict__ h2o_w,
    const float* __restrict__ pre_o,
    const float* __restrict__ hseq,
    float* __restrict__ uout) {
    int k = blockIdx.x, i = threadIdx.x;
    __shared__ float hk[64];
    hk[i] = hseq[k * 64 + i];
    __syncthreads();
    float acc = pre_o[k * 64 + i];
#pragma unroll
    for (int m = 0; m < 64; ++m) acc += h2o_w[i * 72 + 8 + m] * hk[m];
    uout[k * 64 + i] = fast_tanh(acc);
}

__global__ __launch_bounds__(256) void k_ctrl(
    const float* __restrict__ t_in, const float* __restrict__ uo,
    const float* __restrict__ wp, float* __restrict__ out) {
    __shared__ float sm[L_TOT];
    const int tid = threadIdx.x;
    {
        float4* s4 = reinterpret_cast<float4*>(sm);
        const float4* w4 = reinterpret_cast<const float4*>(wp);
        for (int idx = tid; idx < L_TOT / 4; idx += 256) s4[idx] = w4[idx];
    }
    __syncthreads();

    const int r = blockIdx.x * 256 + tid;
    float tval = t_in[r];
    int ti = min((int)(tval * 1024.0f), 1023);
    float4 z[16];
    const float4* ep = reinterpret_cast<const float4*>(uo + ti * 64);
#pragma unroll
    for (int v = 0; v < 16; ++v) z[v] = ep[v];

    float h2[20];
    mlp20<L_UW1, L_UB1, L_UW2, L_UB2>(sm, tval, z, h2);

    float oacc[64];
    float4* op = reinterpret_cast<float4*>(out + (size_t)r * 64);
#pragma unroll
    for (int v = 0; v < 16; ++v) {
        float4 f = op[v];
        oacc[4*v+0] = f.x; oacc[4*v+1] = f.y;
        oacc[4*v+2] = f.z; oacc[4*v+3] = f.w;
    }
    final64<L_UW3, L_UB3, L_CWT + 64 * 64>(sm, h2, oacc);
#pragma unroll
    for (int v = 0; v < 16; ++v) {
        float4 f;
        f.x = oacc[4*v+0]; f.y = oacc[4*v+1];
        f.z = oacc[4*v+2]; f.w = oacc[4*v+3];
        op[v] = f;
    }
}

extern "C" void kernel_launch(void* const* d_in, const int* in_sizes, int n_in,
                              void* d_out, int out_size, void* d_ws, size_t ws_size,
                              hipStream_t stream) {
    const float* t     = (const float*)d_in[0];
    const float* x     = (const float*)d_in[1];
    const float* u     = (const float*)d_in[2];
    const float* i2h_w = (const float*)d_in[3];
    const float* i2h_b = (const float*)d_in[4];
    const float* h2o_w = (const float*)d_in[5];
    const float* h2o_b = (const float*)d_in[6];
    const float* xw1 = (const float*)d_in[7];  const float* xb1 = (const float*)d_in[8];
    const float* xw2 = (const float*)d_in[9];  const float* xb2 = (const float*)d_in[10];
    const float* xw3 = (const float*)d_in[11]; const float* xb3 = (const float*)d_in[12];
    const float* uw1 = (const float*)d_in[13]; const float* ub1 = (const float*)d_in[14];
    const float* uw2 = (const float*)d_in[15]; const float* ub2 = (const float*)d_in[16];
    const float* uw3 = (const float*)d_in[17]; const float* ub3 = (const float*)d_in[18];
    const float* cw  = (const float*)d_in[19]; const float* cb  = (const float*)d_in[20];
    float* out = (float*)d_out;

    float* ws = (float*)d_ws;
    float* pre_i = ws;                 // [0,      65536)
    float* hseq  = ws;                 // alias pre_i: chunk lifetimes disjoint
    float* pre_o = ws + 65536;         // [65536, 131072)
    float* uo    = ws + 131072;        // [131072,196608)
    float* wp    = ws + 196608;        // [196608,211152)
    int*   flag1 = (int*)(ws + 211152);// 16 ints
    int*   flag2 = flag1 + 16;         // 16 ints

    int Bv = in_sizes[0];              // 262144

    hipLaunchKernelGGL(k_repack, dim3((L_TOT + 255) / 256), dim3(256), 0, stream,
                       xw1, uw1, xw2, uw2, xw3, uw3, cw,
                       xb1, xb2, ub1, ub2, xb3, ub3, cb, wp);
    hipLaunchKernelGGL(k_rnn_pre, dim3(256), dim3(256), 0, stream,
                       u, i2h_w, i2h_b, h2o_w, h2o_b, pre_i, pre_o);
    hipMemsetAsync(flag1, 0, 32 * sizeof(int), stream);

    void* kargs[] = { (void*)&t, (void*)&x, (void*)&i2h_w, (void*)&h2o_w,
                      (void*)&pre_i, (void*)&pre_o, (void*)&wp, (void*)&uo,
                      (void*)&hseq, (void*)&flag1, (void*)&flag2,
                      (void*)&out, (void*)&Bv };
    hipError_t cerr = hipLaunchCooperativeKernel((const void*)k_all, dim3(NBLK),
                                                 dim3(256), kargs, 0, stream);
    if (cerr != hipSuccess) {
        // fallback: proven round-9 sequence
        hipLaunchKernelGGL(k_main_r9, dim3(1 + Bv / 256), dim3(256), 0, stream,
                           t, x, i2h_w, pre_i, wp, hseq, out);
        hipLaunchKernelGGL(k_rnn_out, dim3(T_SEQ), dim3(64), 0, stream,
                           h2o_w, pre_o, hseq, uo);
        hipLaunchKernelGGL(k_ctrl, dim3(Bv / 256), dim3(256), 0, stream,
                           t, uo, wp, out);
    }
}

// Round 13
// 403.560 us; speedup vs baseline: 1.6956x; 1.4062x over previous
//
#include <hip/hip_runtime.h>
#include <hip/hip_bf16.h>

#define T_SEQ 1024
#define CHUNK 64
#define NCHUNK 16

__device__ __forceinline__ float fast_sigmoid(float x) {
    return 1.0f / (1.0f + __expf(-x));
}
__device__ __forceinline__ float fast_tanh(float x) {
    float e = __expf(2.0f * x);
    return 1.0f - 2.0f / (e + 1.0f);
}

// K1: precompute u-dependent parts of both RNN linears (+bias)
__global__ __launch_bounds__(256) void k_rnn_pre(
    const float* __restrict__ u,
    const float* __restrict__ i2h_w, const float* __restrict__ i2h_b,
    const float* __restrict__ h2o_w, const float* __restrict__ h2o_b,
    float* __restrict__ pre_i, float* __restrict__ pre_o) {
    int idx = blockIdx.x * 256 + threadIdx.x;   // 0..65535
    int k = idx >> 6, i = idx & 63;
    float a = i2h_b[i], b = h2o_b[i];
#pragma unroll
    for (int c = 0; c < 8; ++c) {
        float uv = u[k * 8 + c];
        a += uv * i2h_w[i * 72 + c];
        b += uv * h2o_w[i * 72 + c];
    }
    pre_i[idx] = a;
    pre_o[idx] = b;
}

// K3: all RNN outputs in parallel (hseq[k] = h BEFORE step k)
__global__ __launch_bounds__(64) void k_rnn_out(
    const float* __restrict__ h2o_w,
    const float* __restrict__ pre_o,
    const float* __restrict__ hseq,
    float* __restrict__ uout) {
    int k = blockIdx.x, i = threadIdx.x;
    __shared__ float hk[64];
    hk[i] = hseq[k * 64 + i];
    __syncthreads();
    float acc = pre_o[k * 64 + i];
#pragma unroll
    for (int m = 0; m < 64; ++m) acc += h2o_w[i * 72 + 8 + m] * hk[m];
    uout[k * 64 + i] = fast_tanh(acc);
}

// ---- packed weight block layout (floats), produced by k_repack ----
#define L_XW1 0
#define L_UW1 1360
#define L_XW2 2720
#define L_UW2 3120
#define L_XW3 3520
#define L_UW3 4800
#define L_CWT 6080
#define L_XB1 14272
#define L_XB2 14292
#define L_UB1 14312
#define L_UB2 14332
#define L_XB3 14352
#define L_UB3 14416
#define L_CB  14480
#define L_TOT 14544   // 58176 bytes

__global__ __launch_bounds__(256) void k_repack(
    const float* __restrict__ xw1, const float* __restrict__ uw1,
    const float* __restrict__ xw2, const float* __restrict__ uw2,
    const float* __restrict__ xw3, const float* __restrict__ uw3,
    const float* __restrict__ cw,
    const float* __restrict__ xb1, const float* __restrict__ xb2,
    const float* __restrict__ ub1, const float* __restrict__ ub2,
    const float* __restrict__ xb3, const float* __restrict__ ub3,
    const float* __restrict__ cb, float* __restrict__ wp) {
    int i = blockIdx.x * 256 + threadIdx.x;
    if (i >= L_TOT) return;
    float v = 0.0f;
    if (i < 1360) {
        int o = i / 68, c = i - o * 68;
        if (c == 0) v = xw1[o * 65];
        else if (c >= 4) v = xw1[o * 65 + c - 3];
    } else if (i < 2720) {
        int j = i - 1360; int o = j / 68, c = j - o * 68;
        if (c == 0) v = uw1[o * 65];
        else if (c >= 4) v = uw1[o * 65 + c - 3];
    } else if (i < 3120) v = xw2[i - 2720];
    else if (i < 3520) v = uw2[i - 3120];
    else if (i < 4800) v = xw3[i - 3520];
    else if (i < 6080) v = uw3[i - 4800];
    else if (i < 14272) {
        int j = i - 6080; int row = j >> 6, s = j & 63;
        v = cw[s * 128 + row];
    }
    else if (i < 14292) v = xb1[i - 14272];
    else if (i < 14312) v = xb2[i - 14292];
    else if (i < 14332) v = ub1[i - 14312];
    else if (i < 14352) v = ub2[i - 14332];
    else if (i < 14416) v = xb3[i - 14352];
    else if (i < 14480) v = ub3[i - 14416];
    else v = cb[i - 14480];
    wp[i] = v;
}

// ---- MLP helpers (read LDS weight block) ----
template <int OW1, int OB1, int OW2, int OB2>
__device__ __forceinline__ void mlp20(const float* __restrict__ sm,
                                      float tval, const float4* z, float* h2) {
    float h1[20];
#pragma unroll 4
    for (int o = 0; o < 20; ++o) {
        const int ro = OW1 + o * 68;
        float a = sm[OB1 + o] + tval * sm[ro];
        const float4* wr = reinterpret_cast<const float4*>(&sm[ro + 4]);
#pragma unroll
        for (int v = 0; v < 16; ++v) {
            float4 w4 = wr[v];
            a += z[v].x * w4.x + z[v].y * w4.y + z[v].z * w4.z + z[v].w * w4.w;
        }
        h1[o] = fast_sigmoid(a);
    }
#pragma unroll 4
    for (int o = 0; o < 20; ++o) {
        float a = sm[OB2 + o];
        const float4* wr = reinterpret_cast<const float4*>(&sm[OW2 + o * 20]);
#pragma unroll
        for (int v = 0; v < 5; ++v) {
            float4 w4 = wr[v];
            a += h1[4*v+0]*w4.x + h1[4*v+1]*w4.y + h1[4*v+2]*w4.z + h1[4*v+3]*w4.w;
        }
        h2[o] = fast_sigmoid(a);
    }
}

template <int OW3, int OB3, int OCWT>
__device__ __forceinline__ void final64(const float* __restrict__ sm,
                                        const float* h2, float* oacc) {
#pragma unroll 2
    for (int o = 0; o < 64; ++o) {
        float a = sm[OB3 + o];
        const float4* wr = reinterpret_cast<const float4*>(&sm[OW3 + o * 20]);
#pragma unroll
        for (int v = 0; v < 5; ++v) {
            float4 w4 = wr[v];
            a += h2[4*v+0]*w4.x + h2[4*v+1]*w4.y + h2[4*v+2]*w4.z + h2[4*v+3]*w4.w;
        }
        float s = fast_sigmoid(a);
        const float4* cr = reinterpret_cast<const float4*>(&sm[OCWT + o * 64]);
#pragma unroll
        for (int v = 0; v < 16; ++v) {
            float4 c4 = cr[v];
            oacc[4*v+0] += s * c4.x; oacc[4*v+1] += s * c4.y;
            oacc[4*v+2] += s * c4.z; oacc[4*v+3] += s * c4.w;
        }
    }
}

// ---- K_MAIN ----
// block 0 = RNN chain, r1-style: 4 waves, 2 barriers/step, wave q computes
//   partial over its 16 h-values (4 b128 reads + 16 fma), wave 0 finalizes
//   (4 part reads + tanh) and writes h in place (safe: reads were pre-barrier1).
//   pre staged per chunk in LDS (r9 pattern); hs history flushed per chunk.
// blocks 1..1024 = state branch (out = cb + state contribution).
#define SMEMF_MAIN 14544   // max(batch weight block 14544, chain 12608)

__global__ __launch_bounds__(256) void k_main(
    const float* __restrict__ t_in, const float* __restrict__ x_in,
    const float* __restrict__ i2h_w,
    const float* __restrict__ pre_i,
    const float* __restrict__ wp,
    float* __restrict__ hseq, float* __restrict__ out) {
    __shared__ float smem[SMEMF_MAIN];
    const int tid = threadIdx.x;
    const int bid = blockIdx.x;

    if (bid == 0) {
        float* pre2 = smem;            // [2][4096]
        float* hs   = smem + 8192;     // [64][64] h BEFORE each step of chunk
        float* part = smem + 12288;    // [4][64]
        float* hcur = smem + 12544;    // [64]
        const int lane = tid & 63;
        const int wv = tid >> 6;

        float wih[16];
#pragma unroll
        for (int j = 0; j < 16; ++j) wih[j] = i2h_w[lane * 72 + 8 + 16 * wv + j];

        {   // stage pre chunk 0
            const float4* pg = reinterpret_cast<const float4*>(pre_i);
            float4* pd = reinterpret_cast<float4*>(pre2);
#pragma unroll
            for (int j = 0; j < 4; ++j) pd[tid * 4 + j] = pg[tid * 4 + j];
        }
        if (tid < 64) hcur[tid] = 0.0f;
        __syncthreads();
        float hreg = 0.0f;                               // wave0: current h
        float prew = (wv == 0) ? pre2[lane] : 0.0f;      // pre for step 0
        float4 pl0, pl1, pl2, pl3;

        for (int c = 0; c < NCHUNK; ++c) {
            const int cb = c & 1;
            const float* pre_c = pre2 + cb * 4096;
            if (c + 1 < NCHUNK) {   // issue next-chunk pre loads (in flight all chunk)
                const float4* pg = reinterpret_cast<const float4*>(pre_i + (c + 1) * 4096);
                pl0 = pg[tid*4+0]; pl1 = pg[tid*4+1]; pl2 = pg[tid*4+2]; pl3 = pg[tid*4+3];
            }
            if (wv == 0) hs[lane] = hreg;                // carry entering chunk
            for (int s = 0; s < CHUNK; ++s) {
                // all 4 waves: read own 16 h values, 16 fma, write partial
                const float4* hb = reinterpret_cast<const float4*>(hcur) + wv * 4;
                float4 b0 = hb[0], b1 = hb[1], b2 = hb[2], b3 = hb[3];
                float a0 = wih[ 0]*b0.x + wih[ 1]*b0.y + wih[ 2]*b0.z + wih[ 3]*b0.w;
                float a1 = wih[ 4]*b1.x + wih[ 5]*b1.y + wih[ 6]*b1.z + wih[ 7]*b1.w;
                float a2 = wih[ 8]*b2.x + wih[ 9]*b2.y + wih[10]*b2.z + wih[11]*b2.w;
                float a3 = wih[12]*b3.x + wih[13]*b3.y + wih[14]*b3.z + wih[15]*b3.w;
                part[wv * 64 + lane] = (a0 + a1) + (a2 + a3);
                __syncthreads();                         // B1: partials ready
                if (wv == 0) {
                    float p0 = part[lane];
                    float p1 = part[64 + lane];
                    float p2 = part[128 + lane];
                    float p3 = part[192 + lane];
                    hreg = fast_tanh((p0 + p1) + (p2 + p3) + prew);
                    hcur[lane] = hreg;                   // in-place: reads were pre-B1
                    if (s + 1 < CHUNK) hs[(s + 1) * 64 + lane] = hreg;
                    prew = pre_c[((s + 1) & 63) * 64 + lane];  // prefetch (s=63 dead)
                }
                __syncthreads();                         // B2: new h visible
            }
            {   // flush this chunk's h history to global hseq
                const float4* hsrc = reinterpret_cast<const float4*>(hs);
                float4* hdst = reinterpret_cast<float4*>(hseq + c * 4096);
#pragma unroll
                for (int j = 0; j < 4; ++j) hdst[tid * 4 + j] = hsrc[tid * 4 + j];
            }
            if (c + 1 < NCHUNK) {   // publish staged pre for next chunk
                float4* pd = reinterpret_cast<float4*>(pre2 + ((c + 1) & 1) * 4096);
                pd[tid*4+0] = pl0; pd[tid*4+1] = pl1; pd[tid*4+2] = pl2; pd[tid*4+3] = pl3;
            }
            __syncthreads();        // flush reads done; pre2[next] published
            if (wv == 0 && c + 1 < NCHUNK) prew = pre2[((c + 1) & 1) * 4096 + lane];
        }
        return;
    }

    // ---- state-branch blocks ----
    {
        float4* s4 = reinterpret_cast<float4*>(smem);
        const float4* w4 = reinterpret_cast<const float4*>(wp);
        for (int idx = tid; idx < L_TOT / 4; idx += 256) s4[idx] = w4[idx];
    }
    __syncthreads();

    const int r = (bid - 1) * 256 + tid;
    float tval = t_in[r];
    float4 z[16];
    const float4* xp = reinterpret_cast<const float4*>(x_in + (size_t)r * 64);
#pragma unroll
    for (int v = 0; v < 16; ++v) z[v] = xp[v];

    float h2[20];
    mlp20<L_XW1, L_XB1, L_XW2, L_XB2>(smem, tval, z, h2);

    float oacc[64];
    {
        const float4* cbp = reinterpret_cast<const float4*>(&smem[L_CB]);
#pragma unroll
        for (int v = 0; v < 16; ++v) {
            float4 c4 = cbp[v];
            oacc[4*v+0] = c4.x; oacc[4*v+1] = c4.y;
            oacc[4*v+2] = c4.z; oacc[4*v+3] = c4.w;
        }
    }
    final64<L_XW3, L_XB3, L_CWT>(smem, h2, oacc);

    float4* op = reinterpret_cast<float4*>(out + (size_t)r * 64);
#pragma unroll
    for (int v = 0; v < 16; ++v) {
        float4 f;
        f.x = oacc[4*v+0]; f.y = oacc[4*v+1];
        f.z = oacc[4*v+2]; f.w = oacc[4*v+3];
        op[v] = f;
    }
}

// ---- K_CTRL: control branch, accumulates into out ----
__global__ __launch_bounds__(256) void k_ctrl(
    const float* __restrict__ t_in, const float* __restrict__ uo,
    const float* __restrict__ wp, float* __restrict__ out) {
    __shared__ float sm[L_TOT];
    const int tid = threadIdx.x;
    {
        float4* s4 = reinterpret_cast<float4*>(sm);
        const float4* w4 = reinterpret_cast<const float4*>(wp);
        for (int idx = tid; idx < L_TOT / 4; idx += 256) s4[idx] = w4[idx];
    }
    __syncthreads();

    const int r = blockIdx.x * 256 + tid;
    float tval = t_in[r];
    int ti = min((int)(tval * 1024.0f), 1023);
    float4 z[16];
    const float4* ep = reinterpret_cast<const float4*>(uo + ti * 64);
#pragma unroll
    for (int v = 0; v < 16; ++v) z[v] = ep[v];

    float h2[20];
    mlp20<L_UW1, L_UB1, L_UW2, L_UB2>(sm, tval, z, h2);

    float oacc[64];
    float4* op = reinterpret_cast<float4*>(out + (size_t)r * 64);
#pragma unroll
    for (int v = 0; v < 16; ++v) {
        float4 f = op[v];
        oacc[4*v+0] = f.x; oacc[4*v+1] = f.y;
        oacc[4*v+2] = f.z; oacc[4*v+3] = f.w;
    }
    final64<L_UW3, L_UB3, L_CWT + 64 * 64>(sm, h2, oacc);
#pragma unroll
    for (int v = 0; v < 16; ++v) {
        float4 f;
        f.x = oacc[4*v+0]; f.y = oacc[4*v+1];
        f.z = oacc[4*v+2]; f.w = oacc[4*v+3];
        op[v] = f;
    }
}

extern "C" void kernel_launch(void* const* d_in, const int* in_sizes, int n_in,
                              void* d_out, int out_size, void* d_ws, size_t ws_size,
                              hipStream_t stream) {
    const float* t     = (const float*)d_in[0];
    const float* x     = (const float*)d_in[1];
    const float* u     = (const float*)d_in[2];
    const float* i2h_w = (const float*)d_in[3];
    const float* i2h_b = (const float*)d_in[4];
    const float* h2o_w = (const float*)d_in[5];
    const float* h2o_b = (const float*)d_in[6];
    const float* xw1 = (const float*)d_in[7];  const float* xb1 = (const float*)d_in[8];
    const float* xw2 = (const float*)d_in[9];  const float* xb2 = (const float*)d_in[10];
    const float* xw3 = (const float*)d_in[11]; const float* xb3 = (const float*)d_in[12];
    const float* uw1 = (const float*)d_in[13]; const float* ub1 = (const float*)d_in[14];
    const float* uw2 = (const float*)d_in[15]; const float* ub2 = (const float*)d_in[16];
    const float* uw3 = (const float*)d_in[17]; const float* ub3 = (const float*)d_in[18];
    const float* cw  = (const float*)d_in[19]; const float* cb  = (const float*)d_in[20];
    float* out = (float*)d_out;

    float* ws = (float*)d_ws;
    // uo aliases pre_i (pre_i dead after k_main; uo written by k_rnn_out after)
    float* pre_i = ws;                 // [0,      65536)
    float* uo    = ws;                 //   alias, used post-k_main
    float* pre_o = ws + 65536;         // [65536, 131072)
    float* hseq  = ws + 131072;        // [131072,196608)
    float* wp    = ws + 196608;        // [196608,211152)

    int Bv = in_sizes[0];              // 262144

    hipLaunchKernelGGL(k_repack, dim3((L_TOT + 255) / 256), dim3(256), 0, stream,
                       xw1, uw1, xw2, uw2, xw3, uw3, cw,
                       xb1, xb2, ub1, ub2, xb3, ub3, cb, wp);
    hipLaunchKernelGGL(k_rnn_pre, dim3(256), dim3(256), 0, stream,
                       u, i2h_w, i2h_b, h2o_w, h2o_b, pre_i, pre_o);
    hipLaunchKernelGGL(k_main, dim3(1 + Bv / 256), dim3(256), 0, stream,
                       t, x, i2h_w, pre_i, wp, hseq, out);
    hipLaunchKernelGGL(k_rnn_out, dim3(T_SEQ), dim3(64), 0, stream,
                       h2o_w, pre_o, hseq, uo);
    hipLaunchKernelGGL(k_ctrl, dim3(Bv / 256), dim3(256), 0, stream,
                       t, uo, wp, out);
}

// Round 14
// 355.093 us; speedup vs baseline: 1.9271x; 1.1365x over previous
//
#include <hip/hip_runtime.h>
#include <hip/hip_bf16.h>

#define T_SEQ 1024
#define CHUNK 64
#define NCHUNK 16

__device__ __forceinline__ float fast_sigmoid(float x) {
    return 1.0f / (1.0f + __expf(-x));
}
__device__ __forceinline__ float fast_tanh(float x) {
    float e = __expf(2.0f * x);
    return 1.0f - 2.0f / (e + 1.0f);
}

// sum within each 4-lane quad via DPP quad_perm (pure VALU, no LDS)
__device__ __forceinline__ float quad_sum(float x) {
    int y1 = __builtin_amdgcn_mov_dpp(__float_as_int(x), 0xB1, 0xF, 0xF, true); // [1,0,3,2]
    float s1 = x + __int_as_float(y1);
    int y2 = __builtin_amdgcn_mov_dpp(__float_as_int(s1), 0x4E, 0xF, 0xF, true); // [2,3,0,1]
    return s1 + __int_as_float(y2);
}

// K1: precompute u-dependent parts of both RNN linears (+bias)
__global__ __launch_bounds__(256) void k_rnn_pre(
    const float* __restrict__ u,
    const float* __restrict__ i2h_w, const float* __restrict__ i2h_b,
    const float* __restrict__ h2o_w, const float* __restrict__ h2o_b,
    float* __restrict__ pre_i, float* __restrict__ pre_o) {
    int idx = blockIdx.x * 256 + threadIdx.x;   // 0..65535
    int k = idx >> 6, i = idx & 63;
    float a = i2h_b[i], b = h2o_b[i];
#pragma unroll
    for (int c = 0; c < 8; ++c) {
        float uv = u[k * 8 + c];
        a += uv * i2h_w[i * 72 + c];
        b += uv * h2o_w[i * 72 + c];
    }
    pre_i[idx] = a;
    pre_o[idx] = b;
}

// K3: all RNN outputs in parallel (hseq[k] = h BEFORE step k)
__global__ __launch_bounds__(64) void k_rnn_out(
    const float* __restrict__ h2o_w,
    const float* __restrict__ pre_o,
    const float* __restrict__ hseq,
    float* __restrict__ uout) {
    int k = blockIdx.x, i = threadIdx.x;
    __shared__ float hk[64];
    hk[i] = hseq[k * 64 + i];
    __syncthreads();
    float acc = pre_o[k * 64 + i];
#pragma unroll
    for (int m = 0; m < 64; ++m) acc += h2o_w[i * 72 + 8 + m] * hk[m];
    uout[k * 64 + i] = fast_tanh(acc);
}

// ---- packed weight block layout (floats), produced by k_repack ----
#define L_XW1 0
#define L_UW1 1360
#define L_XW2 2720
#define L_UW2 3120
#define L_XW3 3520
#define L_UW3 4800
#define L_CWT 6080
#define L_XB1 14272
#define L_XB2 14292
#define L_UB1 14312
#define L_UB2 14332
#define L_XB3 14352
#define L_UB3 14416
#define L_CB  14480
#define L_TOT 14544   // 58176 bytes

__global__ __launch_bounds__(256) void k_repack(
    const float* __restrict__ xw1, const float* __restrict__ uw1,
    const float* __restrict__ xw2, const float* __restrict__ uw2,
    const float* __restrict__ xw3, const float* __restrict__ uw3,
    const float* __restrict__ cw,
    const float* __restrict__ xb1, const float* __restrict__ xb2,
    const float* __restrict__ ub1, const float* __restrict__ ub2,
    const float* __restrict__ xb3, const float* __restrict__ ub3,
    const float* __restrict__ cb, float* __restrict__ wp) {
    int i = blockIdx.x * 256 + threadIdx.x;
    if (i >= L_TOT) return;
    float v = 0.0f;
    if (i < 1360) {
        int o = i / 68, c = i - o * 68;
        if (c == 0) v = xw1[o * 65];
        else if (c >= 4) v = xw1[o * 65 + c - 3];
    } else if (i < 2720) {
        int j = i - 1360; int o = j / 68, c = j - o * 68;
        if (c == 0) v = uw1[o * 65];
        else if (c >= 4) v = uw1[o * 65 + c - 3];
    } else if (i < 3120) v = xw2[i - 2720];
    else if (i < 3520) v = uw2[i - 3120];
    else if (i < 4800) v = xw3[i - 3520];
    else if (i < 6080) v = uw3[i - 4800];
    else if (i < 14272) {
        int j = i - 6080; int row = j >> 6, s = j & 63;
        v = cw[s * 128 + row];
    }
    else if (i < 14292) v = xb1[i - 14272];
    else if (i < 14312) v = xb2[i - 14292];
    else if (i < 14332) v = ub1[i - 14312];
    else if (i < 14352) v = ub2[i - 14332];
    else if (i < 14416) v = xb3[i - 14352];
    else if (i < 14480) v = ub3[i - 14416];
    else v = cb[i - 14480];
    wp[i] = v;
}

// ---- MLP helpers (read LDS weight block) ----
template <int OW1, int OB1, int OW2, int OB2>
__device__ __forceinline__ void mlp20(const float* __restrict__ sm,
                                      float tval, const float4* z, float* h2) {
    float h1[20];
#pragma unroll 4
    for (int o = 0; o < 20; ++o) {
        const int ro = OW1 + o * 68;
        float a = sm[OB1 + o] + tval * sm[ro];
        const float4* wr = reinterpret_cast<const float4*>(&sm[ro + 4]);
#pragma unroll
        for (int v = 0; v < 16; ++v) {
            float4 w4 = wr[v];
            a += z[v].x * w4.x + z[v].y * w4.y + z[v].z * w4.z + z[v].w * w4.w;
        }
        h1[o] = fast_sigmoid(a);
    }
#pragma unroll 4
    for (int o = 0; o < 20; ++o) {
        float a = sm[OB2 + o];
        const float4* wr = reinterpret_cast<const float4*>(&sm[OW2 + o * 20]);
#pragma unroll
        for (int v = 0; v < 5; ++v) {
            float4 w4 = wr[v];
            a += h1[4*v+0]*w4.x + h1[4*v+1]*w4.y + h1[4*v+2]*w4.z + h1[4*v+3]*w4.w;
        }
        h2[o] = fast_sigmoid(a);
    }
}

template <int OW3, int OB3, int OCWT>
__device__ __forceinline__ void final64(const float* __restrict__ sm,
                                        const float* h2, float* oacc) {
#pragma unroll 2
    for (int o = 0; o < 64; ++o) {
        float a = sm[OB3 + o];
        const float4* wr = reinterpret_cast<const float4*>(&sm[OW3 + o * 20]);
#pragma unroll
        for (int v = 0; v < 5; ++v) {
            float4 w4 = wr[v];
            a += h2[4*v+0]*w4.x + h2[4*v+1]*w4.y + h2[4*v+2]*w4.z + h2[4*v+3]*w4.w;
        }
        float s = fast_sigmoid(a);
        const float4* cr = reinterpret_cast<const float4*>(&sm[OCWT + o * 64]);
#pragma unroll
        for (int v = 0; v < 16; ++v) {
            float4 c4 = cr[v];
            oacc[4*v+0] += s * c4.x; oacc[4*v+1] += s * c4.y;
            oacc[4*v+2] += s * c4.z; oacc[4*v+3] += s * c4.w;
        }
    }
}

// ---- K_MAIN ----
// block 0 = RNN chain: 4 waves, ONE barrier/step, ONE LDS round-trip/step.
//   Wave wv owns outputs o = 16wv..16wv+15; 4 lanes per output: lane (t,j)
//   (lane = 4t+j) reads h[16j..16j+16) from hs[s] (4x b128), 16 fma, then
//   DPP quad-reduce (register), + pre (quad-broadcast LDS read), tanh,
//   lane j==0 writes hs[s+1][o]. hs[65][64] rolls in place = the history.
// blocks 1..1024 = state branch (out = cb + state contribution).
#define SMEMF_MAIN 14544   // floats; chain uses 12352

__global__ __launch_bounds__(256) void k_main(
    const float* __restrict__ t_in, const float* __restrict__ x_in,
    const float* __restrict__ i2h_w,
    const float* __restrict__ pre_i,
    const float* __restrict__ wp,
    float* __restrict__ hseq, float* __restrict__ out) {
    __shared__ float smem[SMEMF_MAIN];
    const int tid = threadIdx.x;
    const int bid = blockIdx.x;

    if (bid == 0) {
        float* pre2 = smem;            // [2][4096]
        float* hs   = smem + 8192;     // [65][64]: hs[s] = h BEFORE step s
        const int lane = tid & 63;
        const int wv = tid >> 6;
        const int t = lane >> 2;       // output sub-index 0..15
        const int j = lane & 3;        // input-slice index 0..3
        const int o = 16 * wv + t;     // this lane's output index

        float wih[16];
#pragma unroll
        for (int jj = 0; jj < 16; ++jj) wih[jj] = i2h_w[o * 72 + 8 + 16 * j + jj];

        {   // stage pre chunk 0
            const float4* pg = reinterpret_cast<const float4*>(pre_i);
            float4* pd = reinterpret_cast<float4*>(pre2);
#pragma unroll
            for (int q = 0; q < 4; ++q) pd[tid * 4 + q] = pg[tid * 4 + q];
        }
        if (tid < 64) hs[tid] = 0.0f;  // h before step 0
        __syncthreads();
        float4 pl0, pl1, pl2, pl3;

        for (int c = 0; c < NCHUNK; ++c) {
            const float* pre_c = pre2 + (c & 1) * 4096;
            if (c + 1 < NCHUNK) {   // issue next-chunk pre loads (in flight all chunk)
                const float4* pg = reinterpret_cast<const float4*>(pre_i + (c + 1) * 4096);
                pl0 = pg[tid*4+0]; pl1 = pg[tid*4+1]; pl2 = pg[tid*4+2]; pl3 = pg[tid*4+3];
            }
            for (int s = 0; s < CHUNK; ++s) {
                const float4* hb = reinterpret_cast<const float4*>(hs + s * 64) + 4 * j;
                float4 b0 = hb[0], b1 = hb[1], b2 = hb[2], b3 = hb[3];
                float pre_v = pre_c[s * 64 + o];          // quad-uniform -> broadcast
                float a0 = wih[ 0]*b0.x + wih[ 1]*b0.y + wih[ 2]*b0.z + wih[ 3]*b0.w;
                float a1 = wih[ 4]*b1.x + wih[ 5]*b1.y + wih[ 6]*b1.z + wih[ 7]*b1.w;
                float a2 = wih[ 8]*b2.x + wih[ 9]*b2.y + wih[10]*b2.z + wih[11]*b2.w;
                float a3 = wih[12]*b3.x + wih[13]*b3.y + wih[14]*b3.z + wih[15]*b3.w;
                float tot = quad_sum((a0 + a1) + (a2 + a3));
                float hn = fast_tanh(tot + pre_v);        // redundant in quad
                if (j == 0) hs[(s + 1) * 64 + o] = hn;
                __syncthreads();
            }
            {   // flush hs[0..63] (= h before steps c*64+s) to hseq[c]
                const float4* hsrc = reinterpret_cast<const float4*>(hs);
                float4* hdst = reinterpret_cast<float4*>(hseq + c * 4096);
#pragma unroll
                for (int q = 0; q < 4; ++q) hdst[tid * 4 + q] = hsrc[tid * 4 + q];
            }
            if (c + 1 < NCHUNK) {   // publish staged pre for next chunk
                float4* pd = reinterpret_cast<float4*>(pre2 + ((c + 1) & 1) * 4096);
                pd[tid*4+0] = pl0; pd[tid*4+1] = pl1; pd[tid*4+2] = pl2; pd[tid*4+3] = pl3;
            }
            __syncthreads();        // flush reads done; pre2[next] visible
            if (tid < 64) hs[tid] = hs[4096 + tid];   // carry: hs[64] -> hs[0]
            __syncthreads();
        }
        return;
    }

    // ---- state-branch blocks ----
    {
        float4* s4 = reinterpret_cast<float4*>(smem);
        const float4* w4 = reinterpret_cast<const float4*>(wp);
        for (int idx = tid; idx < L_TOT / 4; idx += 256) s4[idx] = w4[idx];
    }
    __syncthreads();

    const int r = (bid - 1) * 256 + tid;
    float tval = t_in[r];
    float4 z[16];
    const float4* xp = reinterpret_cast<const float4*>(x_in + (size_t)r * 64);
#pragma unroll
    for (int v = 0; v < 16; ++v) z[v] = xp[v];

    float h2[20];
    mlp20<L_XW1, L_XB1, L_XW2, L_XB2>(smem, tval, z, h2);

    float oacc[64];
    {
        const float4* cbp = reinterpret_cast<const float4*>(&smem[L_CB]);
#pragma unroll
        for (int v = 0; v < 16; ++v) {
            float4 c4 = cbp[v];
            oacc[4*v+0] = c4.x; oacc[4*v+1] = c4.y;
            oacc[4*v+2] = c4.z; oacc[4*v+3] = c4.w;
        }
    }
    final64<L_XW3, L_XB3, L_CWT>(smem, h2, oacc);

    float4* op = reinterpret_cast<float4*>(out + (size_t)r * 64);
#pragma unroll
    for (int v = 0; v < 16; ++v) {
        float4 f;
        f.x = oacc[4*v+0]; f.y = oacc[4*v+1];
        f.z = oacc[4*v+2]; f.w = oacc[4*v+3];
        op[v] = f;
    }
}

// ---- K_CTRL: control branch, accumulates into out ----
__global__ __launch_bounds__(256) void k_ctrl(
    const float* __restrict__ t_in, const float* __restrict__ uo,
    const float* __restrict__ wp, float* __restrict__ out) {
    __shared__ float sm[L_TOT];
    const int tid = threadIdx.x;
    {
        float4* s4 = reinterpret_cast<float4*>(sm);
        const float4* w4 = reinterpret_cast<const float4*>(wp);
        for (int idx = tid; idx < L_TOT / 4; idx += 256) s4[idx] = w4[idx];
    }
    __syncthreads();

    const int r = blockIdx.x * 256 + tid;
    float tval = t_in[r];
    int ti = min((int)(tval * 1024.0f), 1023);
    float4 z[16];
    const float4* ep = reinterpret_cast<const float4*>(uo + ti * 64);
#pragma unroll
    for (int v = 0; v < 16; ++v) z[v] = ep[v];

    float h2[20];
    mlp20<L_UW1, L_UB1, L_UW2, L_UB2>(sm, tval, z, h2);

    float oacc[64];
    float4* op = reinterpret_cast<float4*>(out + (size_t)r * 64);
#pragma unroll
    for (int v = 0; v < 16; ++v) {
        float4 f = op[v];
        oacc[4*v+0] = f.x; oacc[4*v+1] = f.y;
        oacc[4*v+2] = f.z; oacc[4*v+3] = f.w;
    }
    final64<L_UW3, L_UB3, L_CWT + 64 * 64>(sm, h2, oacc);
#pragma unroll
    for (int v = 0; v < 16; ++v) {
        float4 f;
        f.x = oacc[4*v+0]; f.y = oacc[4*v+1];
        f.z = oacc[4*v+2]; f.w = oacc[4*v+3];
        op[v] = f;
    }
}

extern "C" void kernel_launch(void* const* d_in, const int* in_sizes, int n_in,
                              void* d_out, int out_size, void* d_ws, size_t ws_size,
                              hipStream_t stream) {
    const float* t     = (const float*)d_in[0];
    const float* x     = (const float*)d_in[1];
    const float* u     = (const float*)d_in[2];
    const float* i2h_w = (const float*)d_in[3];
    const float* i2h_b = (const float*)d_in[4];
    const float* h2o_w = (const float*)d_in[5];
    const float* h2o_b = (const float*)d_in[6];
    const float* xw1 = (const float*)d_in[7];  const float* xb1 = (const float*)d_in[8];
    const float* xw2 = (const float*)d_in[9];  const float* xb2 = (const float*)d_in[10];
    const float* xw3 = (const float*)d_in[11]; const float* xb3 = (const float*)d_in[12];
    const float* uw1 = (const float*)d_in[13]; const float* ub1 = (const float*)d_in[14];
    const float* uw2 = (const float*)d_in[15]; const float* ub2 = (const float*)d_in[16];
    const float* uw3 = (const float*)d_in[17]; const float* ub3 = (const float*)d_in[18];
    const float* cw  = (const float*)d_in[19]; const float* cb  = (const float*)d_in[20];
    float* out = (float*)d_out;

    float* ws = (float*)d_ws;
    // uo aliases pre_i (pre_i dead after k_main; uo written by k_rnn_out after)
    float* pre_i = ws;                 // [0,      65536)
    float* uo    = ws;                 //   alias, used post-k_main
    float* pre_o = ws + 65536;         // [65536, 131072)
    float* hseq  = ws + 131072;        // [131072,196608)
    float* wp    = ws + 196608;        // [196608,211152)

    int Bv = in_sizes[0];              // 262144

    hipLaunchKernelGGL(k_repack, dim3((L_TOT + 255) / 256), dim3(256), 0, stream,
                       xw1, uw1, xw2, uw2, xw3, uw3, cw,
                       xb1, xb2, ub1, ub2, xb3, ub3, cb, wp);
    hipLaunchKernelGGL(k_rnn_pre, dim3(256), dim3(256), 0, stream,
                       u, i2h_w, i2h_b, h2o_w, h2o_b, pre_i, pre_o);
    hipLaunchKernelGGL(k_main, dim3(1 + Bv / 256), dim3(256), 0, stream,
                       t, x, i2h_w, pre_i, wp, hseq, out);
    hipLaunchKernelGGL(k_rnn_out, dim3(T_SEQ), dim3(64), 0, stream,
                       h2o_w, pre_o, hseq, uo);
    hipLaunchKernelGGL(k_ctrl, dim3(Bv / 256), dim3(256), 0, stream,
                       t, uo, wp, out);
}